// Round 8
// baseline (352.796 us; speedup 1.0000x reference)
//
#include <hip/hip_runtime.h>
#include <math.h>
#include <utility>

typedef __attribute__((ext_vector_type(8))) short    bf16x8;
typedef __attribute__((ext_vector_type(4))) float    f32x4;
typedef __attribute__((ext_vector_type(2))) unsigned u32x2;
typedef __attribute__((ext_vector_type(4))) unsigned u32x4;

template<int I, int N, class F>
__device__ __forceinline__ void sfor(F&& f) {
    if constexpr (I < N) { f(std::integral_constant<int, I>{}); sfor<I + 1, N>(static_cast<F&&>(f)); }
}

#define NPT    50000
#define NTILES 6250     // 400000 pts / 64 per tile, exact
#define ZIN_S  40       // shorts per zin row (80 B = 5*16B)
#define Z_S    136      // shorts per z1/z2 row (272 B = 17*16B)
#define LOG2E  1.4426950408889634f

static __device__ __forceinline__ unsigned short bf16r(float f) {   // RNE f32->bf16
    unsigned u = __builtin_bit_cast(unsigned, f);
    u += 0x7FFFu + ((u >> 16) & 1u);
    return (unsigned short)(u >> 16);
}

#if defined(__has_builtin)
#if __has_builtin(__builtin_amdgcn_cvt_pk_bf16_f32)
#define HAVE_CVT_PK_BF16 1
#endif
#if __has_builtin(__builtin_amdgcn_exp2f) && __has_builtin(__builtin_amdgcn_rcpf)
#define HAVE_RAW_TRANS 1
#endif
#endif

static __device__ __forceinline__ unsigned packbf(float a, float b) {
#ifdef HAVE_CVT_PK_BF16
    return __builtin_bit_cast(unsigned, __builtin_amdgcn_cvt_pk_bf16_f32(a, b));
#else
    return (unsigned)bf16r(a) | ((unsigned)bf16r(b) << 16);
#endif
}

#ifdef HAVE_RAW_TRANS
static __device__ __forceinline__ float fexp2(float x) { return __builtin_amdgcn_exp2f(x); }
static __device__ __forceinline__ float frcp(float x)  { return __builtin_amdgcn_rcpf(x); }
#else
static __device__ __forceinline__ float fexp2(float x) { return __exp2f(x); }
static __device__ __forceinline__ float frcp(float x)  { return __frcp_rn(x); }
#endif

// g-weights pre-scaled by -log2e: gate = relu(h * sigmoid(g)) = max(h*rcp(1+2^g'),0)
static __device__ __forceinline__ float gate(float h, float gp) {
    return fmaxf(h * frcp(1.f + fexp2(gp)), 0.f);
}
// out-weights pre-scaled by 2*log2e: tanh(v)*0.5 = 0.5 - rcp(2^v' + 1)
static __device__ __forceinline__ float khalf(float vp) {
    return 0.5f - frcp(fexp2(vp) + 1.f);
}

static __device__ __forceinline__ bf16x8 pack8s(const float* p, float s) { // p 16B-aligned
    f32x4 lo = *reinterpret_cast<const f32x4*>(p);
    f32x4 hi = *reinterpret_cast<const f32x4*>(p + 4);
    u32x4 u = { packbf(lo[0]*s, lo[1]*s), packbf(lo[2]*s, lo[3]*s),
                packbf(hi[0]*s, hi[1]*s), packbf(hi[2]*s, hi[3]*s) };
    return __builtin_bit_cast(bf16x8, u);
}
static __device__ __forceinline__ f32x4 mfma16(bf16x8 a, bf16x8 b, f32x4 c) {
    return __builtin_amdgcn_mfma_f32_16x16x32_bf16(a, b, c, 0, 0, 0);
}

// Block = 512 thr = 8 waves, one 64-point tile per block.
// Wave w owns channel rows [16w,16w+16); waves 0-3 own points [16w,16w+16).
// Round-8: register diet for 6 waves/SIMD (3 blocks/CU = 24 waves):
//  - biases in LDS (broadcast reads), accs chunked to one f32x4 pair,
//  - log2e scales folded into g/out weights at preload (saves per-gate mul).
// Resident regs: a2 frags 32 + a1 frags 8 + acc 8 + rk4 16 + temps ~20 <= 85.
__global__ __launch_bounds__(512, 6) void node_rk4_mfma(
    const float* __restrict__ x0,
    const float* __restrict__ h1_w, const float* __restrict__ h1_b,
    const float* __restrict__ g1_w, const float* __restrict__ g1_b,
    const float* __restrict__ h2_w, const float* __restrict__ h2_b,
    const float* __restrict__ g2_w, const float* __restrict__ g2_b,
    const float* __restrict__ out_w, const float* __restrict__ out_b,
    float* __restrict__ y)
{
    __shared__ __align__(16) short zin[64 * ZIN_S];
    __shared__ __align__(16) short z1s[64 * Z_S];
    __shared__ __align__(16) short z2s[64 * Z_S];
    __shared__ __align__(16) short aow_s[4 * 64 * 8];   // out-layer A-frags [ks][lane]
    __shared__ __align__(16) float bias_s[4 * 128 + 16]; // h1,g1',h2,g2' + vob'

    const int tid  = threadIdx.x;
    const int w    = tid >> 6;        // wave id 0..7
    const int lane = tid & 63;
    const int q    = lane >> 4;       // quad 0..3
    const int m    = lane & 15;       // MFMA row (A) / col (B,C)

    // ---------------- weight preload (once per block) ----------------
    const int row = 16 * w + m;                 // this lane's A-row (channel)
    bf16x8 a2h[4], a2g[4];                      // layer2 A-frags per k-step
    sfor<0, 4>([&](auto KS) {
        constexpr int ks = KS.value;
        a2h[ks] = pack8s(h2_w + row * 128 + ks * 32 + q * 8, 1.0f);
        a2g[ks] = pack8s(g2_w + row * 128 + ks * 32 + q * 8, -LOG2E);
    });
    bf16x8 a1h = {0,0,0,0,0,0,0,0}, a1g = {0,0,0,0,0,0,0,0};
    if (q == 0) {
        f32x4 t1 = *reinterpret_cast<const f32x4*>(h1_w + row * 4);
        f32x4 t2 = *reinterpret_cast<const f32x4*>(g1_w + row * 4);
        u32x4 u1 = { packbf(t1[0], t1[1]), packbf(t1[2], t1[3]), 0u, 0u };
        u32x4 u2 = { packbf(t2[0] * -LOG2E, t2[1] * -LOG2E),
                     packbf(t2[2] * -LOG2E, t2[3] * -LOG2E), 0u, 0u };
        a1h = __builtin_bit_cast(bf16x8, u1);
        a1g = __builtin_bit_cast(bf16x8, u2);
    }
    // out-layer A-frags -> LDS (wave 0 builds; lane-linear, conflict-free reads)
    if (w == 0) {
        sfor<0, 4>([&](auto KS) {
            constexpr int ks = KS.value;
            bf16x8 t = {0,0,0,0,0,0,0,0};
            if (m < 3) t = pack8s(out_w + m * 128 + ks * 32 + q * 8, 2.f * LOG2E);
            *reinterpret_cast<bf16x8*>(&aow_s[(ks * 64 + lane) * 8]) = t;
        });
    }
    // biases -> LDS (C-frag reads are wave-broadcast)
    if (tid < 128) {
        bias_s[tid]       = h1_b[tid];
        bias_s[128 + tid] = g1_b[tid] * -LOG2E;
        bias_s[256 + tid] = h2_b[tid];
        bias_s[384 + tid] = g2_b[tid] * -LOG2E;
    }
    if (tid < 16) bias_s[512 + tid] = (tid < 3) ? out_b[tid] * (2.f * LOG2E) : 0.f;

    // zero zin (pad rows k=4..31 must be 0 for the K-padded layer1 MFMA)
    for (int i = tid; i < 64 * ZIN_S / 2; i += 512) ((unsigned*)zin)[i] = 0u;
    __syncthreads();

    const float third = 1.0f / 3.0f;
    const int tile = blockIdx.x;
    const int cb4 = 16 * w + 4 * q;   // this lane's C-frag channel base

    // RK4 state: waves 0-3, lanes 0-15 (point = tile*64 + w*16 + lane)
    float xc0 = 0.f, xc1 = 0.f, xc2 = 0.f;
    int gbase = 0;
    if (w < 4 && lane < 16) {
        const int pg = tile * 64 + w * 16 + lane;
        const int bb = pg / NPT;
        const int nn = pg - bb * NPT;
        gbase = bb * 3 * NPT + nn;
        xc0 = x0[gbase]; xc1 = x0[gbase + NPT]; xc2 = x0[gbase + 2 * NPT];
    }
    float k1x=0,k1y=0,k1z=0, k2x=0,k2y=0,k2z=0, k3x=0,k3y=0,k3z=0;
    float ax=0, ay=0, az=0;

    #pragma unroll 1
    for (int s = 0; s < 4; ++s) {
        // ---- stage input -> zin (B-frag rows; owner lanes only) ----
        if (w < 4 && lane < 16) {
            float zi0, zi1, zi2, tt;
            if (s == 0)      { zi0 = xc0; zi1 = xc1; zi2 = xc2; tt = 0.f; }
            else if (s == 1) { zi0 = fmaf(k1x, third, xc0);
                               zi1 = fmaf(k1y, third, xc1);
                               zi2 = fmaf(k1z, third, xc2); tt = third; }
            else if (s == 2) { zi0 = xc0 + (k2x - k1x * third);
                               zi1 = xc1 + (k2y - k1y * third);
                               zi2 = xc2 + (k2z - k1z * third); tt = 2.f * third; }
            else             { zi0 = xc0 + (k1x - k2x + k3x);
                               zi1 = xc1 + (k1y - k2y + k3y);
                               zi2 = xc2 + (k1z - k2z + k3z); tt = 1.f; }
            u32x2 pk = { packbf(zi0, zi1), packbf(zi2, tt) };
            *reinterpret_cast<u32x2*>(&zin[(w * 16 + lane) * ZIN_S]) = pk;
        }
        __syncthreads();

        // ---- layer 1 (4->128, K-padded MFMA); one acc pair live ----
        {
            const f32x4 b1h = *reinterpret_cast<const f32x4*>(&bias_s[cb4]);
            const f32x4 b1g = *reinterpret_cast<const f32x4*>(&bias_s[128 + cb4]);
            #pragma unroll 1
            for (int nt = 0; nt < 4; ++nt) {
                bf16x8 bf = *reinterpret_cast<const bf16x8*>(&zin[(nt * 16 + m) * ZIN_S + q * 8]);
                f32x4 ch = mfma16(a1h, bf, b1h);
                f32x4 cg = mfma16(a1g, bf, b1g);
                u32x2 pk = { packbf(gate(ch[0], cg[0]), gate(ch[1], cg[1])),
                             packbf(gate(ch[2], cg[2]), gate(ch[3], cg[3])) };
                *reinterpret_cast<u32x2*>(&z1s[(nt * 16 + m) * Z_S + 16 * w + 4 * q]) = pk;
            }
        }
        __syncthreads();

        // ---- layer 2 (128->128); nt-chunked, bias rides in as C on ks=0 ----
        {
            const f32x4 b2h = *reinterpret_cast<const f32x4*>(&bias_s[256 + cb4]);
            const f32x4 b2g = *reinterpret_cast<const f32x4*>(&bias_s[384 + cb4]);
            #pragma unroll 1
            for (int nt = 0; nt < 4; ++nt) {
                const short* zrow = &z1s[(nt * 16 + m) * Z_S + q * 8];
                bf16x8 bf0 = *reinterpret_cast<const bf16x8*>(zrow);
                f32x4 ch = mfma16(a2h[0], bf0, b2h);
                f32x4 cg = mfma16(a2g[0], bf0, b2g);
                sfor<1, 4>([&](auto KS) {
                    constexpr int ks = KS.value;
                    bf16x8 bf = *reinterpret_cast<const bf16x8*>(zrow + ks * 32);
                    ch = mfma16(a2h[ks], bf, ch);
                    cg = mfma16(a2g[ks], bf, cg);
                });
                u32x2 pk = { packbf(gate(ch[0], cg[0]), gate(ch[1], cg[1])),
                             packbf(gate(ch[2], cg[2]), gate(ch[3], cg[3])) };
                *reinterpret_cast<u32x2*>(&z2s[(nt * 16 + m) * Z_S + 16 * w + 4 * q]) = pk;
            }
        }
        __syncthreads();

        // ---- out layer (128->3, M padded to 16); waves 0-3, 16 pts each ----
        if (w < 4) {
            f32x4 vc = *reinterpret_cast<const f32x4*>(&bias_s[512 + 4 * q]);
            sfor<0, 4>([&](auto KS) {
                constexpr int ks = KS.value;
                bf16x8 af = *reinterpret_cast<const bf16x8*>(&aow_s[(ks * 64 + lane) * 8]);
                bf16x8 bf = *reinterpret_cast<const bf16x8*>(&z2s[(w * 16 + m) * Z_S + ks * 32 + q * 8]);
                vc = mfma16(af, bf, vc);
            });
            // channels live in quad-0 regs 0..2; khalf = tanh*0.5 (scale folded)
            const float kx = khalf(vc[0]);
            const float ky = khalf(vc[1]);
            const float kz = khalf(vc[2]);

            if (s == 0)      { k1x=kx;k1y=ky;k1z=kz; ax=kx;ay=ky;az=kz; }
            else if (s == 1) { k2x=kx;k2y=ky;k2z=kz;
                               ax=fmaf(3.f,kx,ax); ay=fmaf(3.f,ky,ay); az=fmaf(3.f,kz,az); }
            else if (s == 2) { k3x=kx;k3y=ky;k3z=kz;
                               ax=fmaf(3.f,kx,ax); ay=fmaf(3.f,ky,ay); az=fmaf(3.f,kz,az); }
            else             { ax+=kx; ay+=ky; az+=kz; }
        }
    }

    if (w < 4 && lane < 16) {
        y[gbase]           = fmaf(0.125f, ax, xc0);
        y[gbase + NPT]     = fmaf(0.125f, ay, xc1);
        y[gbase + 2 * NPT] = fmaf(0.125f, az, xc2);
    }
}

extern "C" void kernel_launch(void* const* d_in, const int* in_sizes, int n_in,
                              void* d_out, int out_size, void* d_ws, size_t ws_size,
                              hipStream_t stream) {
    (void)in_sizes; (void)n_in; (void)d_ws; (void)ws_size; (void)out_size;
    const float* x0    = (const float*)d_in[0];
    const float* h1_w  = (const float*)d_in[1];
    const float* h1_b  = (const float*)d_in[2];
    const float* g1_w  = (const float*)d_in[3];
    const float* g1_b  = (const float*)d_in[4];
    const float* h2_w  = (const float*)d_in[5];
    const float* h2_b  = (const float*)d_in[6];
    const float* g2_w  = (const float*)d_in[7];
    const float* g2_b  = (const float*)d_in[8];
    const float* out_w = (const float*)d_in[9];
    const float* out_b = (const float*)d_in[10];
    float* y = (float*)d_out;

    // one 64-pt tile per 512-thread block
    node_rk4_mfma<<<NTILES, 512, 0, stream>>>(
        x0, h1_w, h1_b, g1_w, g1_b, h2_w, h2_b, g2_w, g2_b, out_w, out_b, y);
}

// Round 9
// 300.779 us; speedup vs baseline: 1.1729x; 1.1729x over previous
//
#include <hip/hip_runtime.h>
#include <math.h>
#include <utility>

typedef __attribute__((ext_vector_type(8))) short    bf16x8;
typedef __attribute__((ext_vector_type(4))) float    f32x4;
typedef __attribute__((ext_vector_type(2))) unsigned u32x2;
typedef __attribute__((ext_vector_type(4))) unsigned u32x4;

template<int I, int N, class F>
__device__ __forceinline__ void sfor(F&& f) {
    if constexpr (I < N) { f(std::integral_constant<int, I>{}); sfor<I + 1, N>(static_cast<F&&>(f)); }
}

#define NPT    50000
#define NTILES 6250     // 400000 pts / 64 per tile, exact
#define ZIN_S  40       // shorts per zin row (80 B = 5*16B)
#define Z_S    136      // shorts per z1/z2 row (272 B = 17*16B)
#define LOG2E  1.4426950408889634f

static __device__ __forceinline__ unsigned short bf16r(float f) {   // RNE f32->bf16
    unsigned u = __builtin_bit_cast(unsigned, f);
    u += 0x7FFFu + ((u >> 16) & 1u);
    return (unsigned short)(u >> 16);
}

#if defined(__has_builtin)
#if __has_builtin(__builtin_amdgcn_cvt_pk_bf16_f32)
#define HAVE_CVT_PK_BF16 1
#endif
#if __has_builtin(__builtin_amdgcn_exp2f) && __has_builtin(__builtin_amdgcn_rcpf)
#define HAVE_RAW_TRANS 1
#endif
#endif

static __device__ __forceinline__ unsigned packbf(float a, float b) {
#ifdef HAVE_CVT_PK_BF16
    return __builtin_bit_cast(unsigned, __builtin_amdgcn_cvt_pk_bf16_f32(a, b));
#else
    return (unsigned)bf16r(a) | ((unsigned)bf16r(b) << 16);
#endif
}

#ifdef HAVE_RAW_TRANS
static __device__ __forceinline__ float fexp2(float x) { return __builtin_amdgcn_exp2f(x); }
static __device__ __forceinline__ float frcp(float x)  { return __builtin_amdgcn_rcpf(x); }
#else
static __device__ __forceinline__ float fexp2(float x) { return __exp2f(x); }
static __device__ __forceinline__ float frcp(float x)  { return __frcp_rn(x); }
#endif

// g-weights pre-scaled by -log2e: gate = relu(h * sigmoid(g)) = max(h*rcp(1+2^g'),0)
static __device__ __forceinline__ float gate(float h, float gp) {
    return fmaxf(h * frcp(1.f + fexp2(gp)), 0.f);
}
// out-weights pre-scaled by 2*log2e: tanh(v)*0.5 = 0.5 - rcp(2^v' + 1)
static __device__ __forceinline__ float khalf(float vp) {
    return 0.5f - frcp(fexp2(vp) + 1.f);
}

static __device__ __forceinline__ bf16x8 pack8s(const float* p, float s) { // p 16B-aligned
    f32x4 lo = *reinterpret_cast<const f32x4*>(p);
    f32x4 hi = *reinterpret_cast<const f32x4*>(p + 4);
    u32x4 u = { packbf(lo[0]*s, lo[1]*s), packbf(lo[2]*s, lo[3]*s),
                packbf(hi[0]*s, hi[1]*s), packbf(hi[2]*s, hi[3]*s) };
    return __builtin_bit_cast(bf16x8, u);
}
static __device__ __forceinline__ f32x4 mfma16(bf16x8 a, bf16x8 b, f32x4 c) {
    return __builtin_amdgcn_mfma_f32_16x16x32_bf16(a, b, c, 0, 0, 0);
}

// Block = 512 thr = 8 waves, one 64-point tile per block.
// Wave w owns channel rows [16w,16w+16); waves 0-3 own points [16w,16w+16).
// Round-9: (512,5) -> 102-reg cap (R8's (512,6)=85 spilled 0.5 GB; structural
// need is ~90). Layer-1 A-frags also moved to LDS (8 B/channel, rebuilt per
// stage) to keep persistent regs ~50 + a2 frags 32. 20 waves/CU target.
__global__ __launch_bounds__(512, 5) void node_rk4_mfma(
    const float* __restrict__ x0,
    const float* __restrict__ h1_w, const float* __restrict__ h1_b,
    const float* __restrict__ g1_w, const float* __restrict__ g1_b,
    const float* __restrict__ h2_w, const float* __restrict__ h2_b,
    const float* __restrict__ g2_w, const float* __restrict__ g2_b,
    const float* __restrict__ out_w, const float* __restrict__ out_b,
    float* __restrict__ y)
{
    __shared__ __align__(16) short zin[64 * ZIN_S];
    __shared__ __align__(16) short z1s[64 * Z_S];
    __shared__ __align__(16) short z2s[64 * Z_S];
    __shared__ __align__(16) short aow_s[4 * 64 * 8];    // out-layer A-frags [ks][lane]
    __shared__ __align__(16) float bias_s[4 * 128 + 16]; // h1,g1',h2,g2' + vob'
    __shared__ __align__(8)  unsigned a1_s[2 * 256];     // layer1 A rows: h [ch*2], g [512.. wait see below]

    const int tid  = threadIdx.x;
    const int w    = tid >> 6;        // wave id 0..7
    const int lane = tid & 63;
    const int q    = lane >> 4;       // quad 0..3
    const int m    = lane & 15;       // MFMA row (A) / col (B,C)

    // ---------------- weight preload (once per block) ----------------
    const int row = 16 * w + m;                 // this lane's A-row (channel)
    bf16x8 a2h[4], a2g[4];                      // layer2 A-frags per k-step (32 regs)
    sfor<0, 4>([&](auto KS) {
        constexpr int ks = KS.value;
        a2h[ks] = pack8s(h2_w + row * 128 + ks * 32 + q * 8, 1.0f);
        a2g[ks] = pack8s(g2_w + row * 128 + ks * 32 + q * 8, -LOG2E);
    });
    // layer1 A rows -> LDS compact (4 bf16 = 8 B per channel, h then g)
    if (tid < 128) {
        const f32x4 t1 = *reinterpret_cast<const f32x4*>(h1_w + tid * 4);
        const f32x4 t2 = *reinterpret_cast<const f32x4*>(g1_w + tid * 4);
        a1_s[tid * 2]           = packbf(t1[0], t1[1]);
        a1_s[tid * 2 + 1]       = packbf(t1[2], t1[3]);
        a1_s[256 + tid * 2]     = packbf(t2[0] * -LOG2E, t2[1] * -LOG2E);
        a1_s[256 + tid * 2 + 1] = packbf(t2[2] * -LOG2E, t2[3] * -LOG2E);
    }
    // out-layer A-frags -> LDS (wave 0 builds; lane-linear, conflict-free reads)
    if (w == 0) {
        sfor<0, 4>([&](auto KS) {
            constexpr int ks = KS.value;
            bf16x8 t = {0,0,0,0,0,0,0,0};
            if (m < 3) t = pack8s(out_w + m * 128 + ks * 32 + q * 8, 2.f * LOG2E);
            *reinterpret_cast<bf16x8*>(&aow_s[(ks * 64 + lane) * 8]) = t;
        });
    }
    // biases -> LDS (C-frag reads are wave-broadcast)
    if (tid < 128) {
        bias_s[tid]       = h1_b[tid];
        bias_s[128 + tid] = g1_b[tid] * -LOG2E;
        bias_s[256 + tid] = h2_b[tid];
        bias_s[384 + tid] = g2_b[tid] * -LOG2E;
    }
    if (tid < 16) bias_s[512 + tid] = (tid < 3) ? out_b[tid] * (2.f * LOG2E) : 0.f;

    // zero zin (pad rows k=4..31 must be 0 for the K-padded layer1 MFMA)
    for (int i = tid; i < 64 * ZIN_S / 2; i += 512) ((unsigned*)zin)[i] = 0u;
    __syncthreads();

    const float third = 1.0f / 3.0f;
    const int tile = blockIdx.x;
    const int cb4 = 16 * w + 4 * q;   // this lane's C-frag channel base

    // RK4 state: waves 0-3, lanes 0-15 (point = tile*64 + w*16 + lane)
    float xc0 = 0.f, xc1 = 0.f, xc2 = 0.f;
    int gbase = 0;
    if (w < 4 && lane < 16) {
        const int pg = tile * 64 + w * 16 + lane;
        const int bb = pg / NPT;
        const int nn = pg - bb * NPT;
        gbase = bb * 3 * NPT + nn;
        xc0 = x0[gbase]; xc1 = x0[gbase + NPT]; xc2 = x0[gbase + 2 * NPT];
    }
    float k1x=0,k1y=0,k1z=0, k2x=0,k2y=0,k2z=0, k3x=0,k3y=0,k3z=0;
    float ax=0, ay=0, az=0;

    #pragma unroll 1
    for (int s = 0; s < 4; ++s) {
        // ---- stage input -> zin (B-frag rows; owner lanes only) ----
        if (w < 4 && lane < 16) {
            float zi0, zi1, zi2, tt;
            if (s == 0)      { zi0 = xc0; zi1 = xc1; zi2 = xc2; tt = 0.f; }
            else if (s == 1) { zi0 = fmaf(k1x, third, xc0);
                               zi1 = fmaf(k1y, third, xc1);
                               zi2 = fmaf(k1z, third, xc2); tt = third; }
            else if (s == 2) { zi0 = xc0 + (k2x - k1x * third);
                               zi1 = xc1 + (k2y - k1y * third);
                               zi2 = xc2 + (k2z - k1z * third); tt = 2.f * third; }
            else             { zi0 = xc0 + (k1x - k2x + k3x);
                               zi1 = xc1 + (k1y - k2y + k3y);
                               zi2 = xc2 + (k1z - k2z + k3z); tt = 1.f; }
            u32x2 pk = { packbf(zi0, zi1), packbf(zi2, tt) };
            *reinterpret_cast<u32x2*>(&zin[(w * 16 + lane) * ZIN_S]) = pk;
        }
        __syncthreads();

        // ---- layer 1 (4->128, K-padded MFMA); A-frags rebuilt from LDS ----
        {
            bf16x8 a1h = {0,0,0,0,0,0,0,0}, a1g = {0,0,0,0,0,0,0,0};
            if (q == 0) {
                u32x2 th = *reinterpret_cast<const u32x2*>(&a1_s[row * 2]);
                u32x2 tg = *reinterpret_cast<const u32x2*>(&a1_s[256 + row * 2]);
                u32x4 uh = { th[0], th[1], 0u, 0u };
                u32x4 ug = { tg[0], tg[1], 0u, 0u };
                a1h = __builtin_bit_cast(bf16x8, uh);
                a1g = __builtin_bit_cast(bf16x8, ug);
            }
            const f32x4 b1h = *reinterpret_cast<const f32x4*>(&bias_s[cb4]);
            const f32x4 b1g = *reinterpret_cast<const f32x4*>(&bias_s[128 + cb4]);
            #pragma unroll 1
            for (int nt = 0; nt < 4; ++nt) {
                bf16x8 bf = *reinterpret_cast<const bf16x8*>(&zin[(nt * 16 + m) * ZIN_S + q * 8]);
                f32x4 ch = mfma16(a1h, bf, b1h);
                f32x4 cg = mfma16(a1g, bf, b1g);
                u32x2 pk = { packbf(gate(ch[0], cg[0]), gate(ch[1], cg[1])),
                             packbf(gate(ch[2], cg[2]), gate(ch[3], cg[3])) };
                *reinterpret_cast<u32x2*>(&z1s[(nt * 16 + m) * Z_S + 16 * w + 4 * q]) = pk;
            }
        }
        __syncthreads();

        // ---- layer 2 (128->128); nt-chunked, bias rides in as C on ks=0 ----
        {
            const f32x4 b2h = *reinterpret_cast<const f32x4*>(&bias_s[256 + cb4]);
            const f32x4 b2g = *reinterpret_cast<const f32x4*>(&bias_s[384 + cb4]);
            #pragma unroll 1
            for (int nt = 0; nt < 4; ++nt) {
                const short* zrow = &z1s[(nt * 16 + m) * Z_S + q * 8];
                bf16x8 bf0 = *reinterpret_cast<const bf16x8*>(zrow);
                f32x4 ch = mfma16(a2h[0], bf0, b2h);
                f32x4 cg = mfma16(a2g[0], bf0, b2g);
                sfor<1, 4>([&](auto KS) {
                    constexpr int ks = KS.value;
                    bf16x8 bf = *reinterpret_cast<const bf16x8*>(zrow + ks * 32);
                    ch = mfma16(a2h[ks], bf, ch);
                    cg = mfma16(a2g[ks], bf, cg);
                });
                u32x2 pk = { packbf(gate(ch[0], cg[0]), gate(ch[1], cg[1])),
                             packbf(gate(ch[2], cg[2]), gate(ch[3], cg[3])) };
                *reinterpret_cast<u32x2*>(&z2s[(nt * 16 + m) * Z_S + 16 * w + 4 * q]) = pk;
            }
        }
        __syncthreads();

        // ---- out layer (128->3, M padded to 16); waves 0-3, 16 pts each ----
        if (w < 4) {
            f32x4 vc = *reinterpret_cast<const f32x4*>(&bias_s[512 + 4 * q]);
            sfor<0, 4>([&](auto KS) {
                constexpr int ks = KS.value;
                bf16x8 af = *reinterpret_cast<const bf16x8*>(&aow_s[(ks * 64 + lane) * 8]);
                bf16x8 bf = *reinterpret_cast<const bf16x8*>(&z2s[(w * 16 + m) * Z_S + ks * 32 + q * 8]);
                vc = mfma16(af, bf, vc);
            });
            // channels live in quad-0 regs 0..2; khalf = tanh*0.5 (scale folded)
            const float kx = khalf(vc[0]);
            const float ky = khalf(vc[1]);
            const float kz = khalf(vc[2]);

            if (s == 0)      { k1x=kx;k1y=ky;k1z=kz; ax=kx;ay=ky;az=kz; }
            else if (s == 1) { k2x=kx;k2y=ky;k2z=kz;
                               ax=fmaf(3.f,kx,ax); ay=fmaf(3.f,ky,ay); az=fmaf(3.f,kz,az); }
            else if (s == 2) { k3x=kx;k3y=ky;k3z=kz;
                               ax=fmaf(3.f,kx,ax); ay=fmaf(3.f,ky,ay); az=fmaf(3.f,kz,az); }
            else             { ax+=kx; ay+=ky; az+=kz; }
        }
    }

    if (w < 4 && lane < 16) {
        y[gbase]           = fmaf(0.125f, ax, xc0);
        y[gbase + NPT]     = fmaf(0.125f, ay, xc1);
        y[gbase + 2 * NPT] = fmaf(0.125f, az, xc2);
    }
}

extern "C" void kernel_launch(void* const* d_in, const int* in_sizes, int n_in,
                              void* d_out, int out_size, void* d_ws, size_t ws_size,
                              hipStream_t stream) {
    (void)in_sizes; (void)n_in; (void)d_ws; (void)ws_size; (void)out_size;
    const float* x0    = (const float*)d_in[0];
    const float* h1_w  = (const float*)d_in[1];
    const float* h1_b  = (const float*)d_in[2];
    const float* g1_w  = (const float*)d_in[3];
    const float* g1_b  = (const float*)d_in[4];
    const float* h2_w  = (const float*)d_in[5];
    const float* h2_b  = (const float*)d_in[6];
    const float* g2_w  = (const float*)d_in[7];
    const float* g2_b  = (const float*)d_in[8];
    const float* out_w = (const float*)d_in[9];
    const float* out_b = (const float*)d_in[10];
    float* y = (float*)d_out;

    // one 64-pt tile per 512-thread block
    node_rk4_mfma<<<NTILES, 512, 0, stream>>>(
        x0, h1_w, h1_b, g1_w, g1_b, h2_w, h2_b, g2_w, g2_b, out_w, out_b, y);
}